// Round 1
// baseline (90.829 us; speedup 1.0000x reference)
//
#include <hip/hip_runtime.h>
#include <hip/hip_bf16.h>

// PHOG: lap = dw3x3(x, laplacian); gx,gy = dw3x3(lap, sobel); mag/ang -> 9-bin
// hist over pyramid cells (1+4+16), L1-ish then L2 normalize.
// Kernel 1: one block per (bc, 64x64 cell) -> raw level-2 histogram [512][16][9] in ws.
// Kernel 2: aggregate levels, normalize, write out [32][1][336][9].

#define H_IMG 256
#define W_IMG 256

// sin/cos of bin boundaries 10,30,...,170 degrees
__device__ __constant__ float BSIN[9] = {
    0.17364817766693033f, 0.5f, 0.766044443118978f, 0.9396926207859084f, 1.0f,
    0.9396926207859084f, 0.766044443118978f, 0.5f, 0.17364817766693041f};
__device__ __constant__ float BCOS[9] = {
    0.984807753012208f, 0.8660254037844387f, 0.6427876096865393f, 0.3420201433256687f, 0.0f,
    -0.3420201433256688f, -0.6427876096865393f, -0.8660254037844387f, -0.984807753012208f};

__device__ __forceinline__ void load_xrow(const float* xs, int row, int cb, float r[8]) {
  const float* p = xs + row * 72 + cb;   // cb is even -> 8B aligned
  float2 a = *reinterpret_cast<const float2*>(p);
  float2 b = *reinterpret_cast<const float2*>(p + 2);
  float2 c = *reinterpret_cast<const float2*>(p + 4);
  float2 d = *reinterpret_cast<const float2*>(p + 6);
  r[0] = a.x; r[1] = a.y; r[2] = b.x; r[3] = b.y;
  r[4] = c.x; r[5] = c.y; r[6] = d.x; r[7] = d.y;
}

// lap row from x rows u (above), m (center), d (below); mask edge cols/rows to 0
__device__ __forceinline__ void lap_row(float dst[6], const float u[8], const float m[8],
                                        const float d[8], float wm0, float wm5, float rowm) {
#pragma unroll
  for (int c = 0; c < 6; ++c) {
    float v = (u[c + 1] + d[c + 1]) + fmaf(-4.f, m[c + 1], m[c] + m[c + 2]);
    dst[c] = v * rowm;
  }
  dst[0] *= wm0;
  dst[5] *= wm5;
}

// gradient + binning + hist accumulate for one output row (4 px) from lap rows A,B,C
__device__ __forceinline__ void out_row(const float A[6], const float B[6], const float C[6],
                                        float h[9]) {
  float cs[6], dd[6];
#pragma unroll
  for (int c = 0; c < 6; ++c) {
    cs[c] = A[c] + fmaf(2.f, B[c], C[c]);
    dd[c] = C[c] - A[c];
  }
#pragma unroll
  for (int c = 0; c < 4; ++c) {
    float gx = cs[c + 2] - cs[c];
    float gy = fmaf(2.f, dd[c + 1], dd[c] + dd[c + 2]);
    float mag = sqrtf(fmaf(gx, gx, fmaf(gy, gy, 1e-8f)));
    // normalize direction to upper half-plane (ang in [0,180))
    bool neg = (gy < 0.f) || ((gy == 0.f) && (gx < 0.f));
    float fx = neg ? -gx : gx;
    float fy = neg ? -gy : gy;
    int cnt = 0;  // count of boundaries b_i <= ang
#pragma unroll
    for (int i = 0; i < 9; ++i) {
      float t = fmaf(BSIN[i], fx, -(BCOS[i] * fy));  // >0 <=> ang < b_i
      cnt += (t <= 0.f) ? 1 : 0;
    }
    int bin = (cnt == 9) ? 0 : cnt;
#pragma unroll
    for (int k = 0; k < 9; ++k) h[k] += (bin == k) ? mag : 0.f;
  }
}

__global__ __launch_bounds__(256) void phog_hist_kernel(const float* __restrict__ x,
                                                        float* __restrict__ hist2) {
  const int tile = blockIdx.x;  // 0..15 == level-2 cell id (cellr*4+cellc)
  const int bc = blockIdx.y;    // 0..511
  const int R0 = (tile >> 2) * 64;
  const int C0 = (tile & 3) * 64;
  const int tid = threadIdx.x;

  __shared__ float xs[68 * 72];  // rows R0-2..R0+65, cols C0-4..C0+67
  __shared__ float hred[4][9];

  const float* xim = x + (size_t)bc * (H_IMG * W_IMG);

  // Stage A: global -> LDS, float4 aligned (col base C0-4 is 4-aligned)
  for (int i = tid; i < 68 * 18; i += 256) {
    int row = i / 18;
    int c4 = i - row * 18;
    int gr = R0 + row - 2;
    int gc = C0 + c4 * 4 - 4;
    float4 v;
    if ((unsigned)gr < 256u && (unsigned)gc < 253u) {
      v = *reinterpret_cast<const float4*>(&xim[gr * W_IMG + gc]);
    } else if ((unsigned)gr < 256u) {
      v.x = ((unsigned)(gc + 0) < 256u) ? xim[gr * W_IMG + gc + 0] : 0.f;
      v.y = ((unsigned)(gc + 1) < 256u) ? xim[gr * W_IMG + gc + 1] : 0.f;
      v.z = ((unsigned)(gc + 2) < 256u) ? xim[gr * W_IMG + gc + 2] : 0.f;
      v.w = ((unsigned)(gc + 3) < 256u) ? xim[gr * W_IMG + gc + 3] : 0.f;
    } else {
      v = make_float4(0.f, 0.f, 0.f, 0.f);
    }
    *reinterpret_cast<float4*>(&xs[row * 72 + c4 * 4]) = v;
  }
  __syncthreads();

  const int tcol = tid & 15;
  const int trow = tid >> 4;
  const int cb = 4 * tcol + 2;  // xs col of window col 0 (global C0+4*tcol-2)

  // edge masks: lap values at global row/col -1 or 256 must be zero
  float wm0 = (C0 + 4 * tcol - 1 >= 0) ? 1.f : 0.f;
  float wm5 = (C0 + 4 * tcol + 4 <= 255) ? 1.f : 0.f;
  float rm0 = (R0 + 4 * trow - 1 >= 0) ? 1.f : 0.f;
  float rm5 = (R0 + 4 * trow + 4 <= 255) ? 1.f : 0.f;

  float h[9];
#pragma unroll
  for (int k = 0; k < 9; ++k) h[k] = 0.f;

  float xr0[8], xr1[8], xr2[8], lA[6], lB[6], lC[6];
  const int rb = 4 * trow;

  load_xrow(xs, rb + 0, cb, xr0);
  load_xrow(xs, rb + 1, cb, xr1);
  load_xrow(xs, rb + 2, cb, xr2);
  lap_row(lA, xr0, xr1, xr2, wm0, wm5, rm0);      // lap row 0
  load_xrow(xs, rb + 3, cb, xr0);
  lap_row(lB, xr1, xr2, xr0, wm0, wm5, 1.f);      // lap row 1
  load_xrow(xs, rb + 4, cb, xr1);
  lap_row(lC, xr2, xr0, xr1, wm0, wm5, 1.f);      // lap row 2
  out_row(lA, lB, lC, h);                         // out row 0
  load_xrow(xs, rb + 5, cb, xr2);
  lap_row(lA, xr0, xr1, xr2, wm0, wm5, 1.f);      // lap row 3
  out_row(lB, lC, lA, h);                         // out row 1
  load_xrow(xs, rb + 6, cb, xr0);
  lap_row(lB, xr1, xr2, xr0, wm0, wm5, 1.f);      // lap row 4
  out_row(lC, lA, lB, h);                         // out row 2
  load_xrow(xs, rb + 7, cb, xr1);
  lap_row(lC, xr2, xr0, xr1, wm0, wm5, rm5);      // lap row 5
  out_row(lA, lB, lC, h);                         // out row 3

  // wave reduce (64 lanes), then cross-wave via LDS
#pragma unroll
  for (int k = 0; k < 9; ++k) {
    float v = h[k];
#pragma unroll
    for (int off = 32; off > 0; off >>= 1) v += __shfl_xor(v, off);
    h[k] = v;
  }
  int lane = tid & 63;
  int wave = tid >> 6;
  if (lane == 0) {
#pragma unroll
    for (int k = 0; k < 9; ++k) hred[wave][k] = h[k];
  }
  __syncthreads();
  if (tid < 9) {
    float s = hred[0][tid] + hred[1][tid] + hred[2][tid] + hred[3][tid];
    hist2[(bc * 16 + tile) * 9 + tid] = s;
  }
}

__global__ __launch_bounds__(256) void phog_norm_kernel(const float* __restrict__ hist2,
                                                        float* __restrict__ out) {
  int t = blockIdx.x * 256 + threadIdx.x;
  if (t >= 32 * 336) return;
  int b = t / 336;
  int r = t - b * 336;

  float h[9];
  if (r < 16) {
    // level 0: sum all 16 cells of channel c=r
    const float* p = hist2 + (b * 16 + r) * 144;
#pragma unroll
    for (int k = 0; k < 9; ++k) {
      float s = 0.f;
#pragma unroll
      for (int cell = 0; cell < 16; ++cell) s += p[cell * 9 + k];
      h[k] = s;
    }
  } else if (r < 80) {
    // level 1: 4 cells per channel; cell (r1,c1) = sum of 2x2 level-2 cells
    int q = r - 16;
    int c = q >> 2;
    int cell = q & 3;
    int r1 = cell >> 1, c1 = cell & 1;
    const float* p = hist2 + (b * 16 + c) * 144;
    int i00 = ((2 * r1) * 4 + 2 * c1) * 9;
    int i01 = ((2 * r1) * 4 + 2 * c1 + 1) * 9;
    int i10 = ((2 * r1 + 1) * 4 + 2 * c1) * 9;
    int i11 = ((2 * r1 + 1) * 4 + 2 * c1 + 1) * 9;
#pragma unroll
    for (int k = 0; k < 9; ++k) h[k] = (p[i00 + k] + p[i01 + k]) + (p[i10 + k] + p[i11 + k]);
  } else {
    // level 2: direct
    int q = r - 80;
    int c = q >> 4;
    int cell = q & 15;
    const float* p = hist2 + ((b * 16 + c) * 16 + cell) * 9;
#pragma unroll
    for (int k = 0; k < 9; ++k) h[k] = p[k];
  }

  float s = 0.f;
#pragma unroll
  for (int k = 0; k < 9; ++k) s += h[k];
  float inv = 1.f / (s + 1e-8f);
#pragma unroll
  for (int k = 0; k < 9; ++k) h[k] *= inv;
  float n2 = 0.f;
#pragma unroll
  for (int k = 0; k < 9; ++k) n2 = fmaf(h[k], h[k], n2);
  float nrm = sqrtf(n2);
  float inv2 = 1.f / fmaxf(nrm, 1e-12f);
#pragma unroll
  for (int k = 0; k < 9; ++k) out[t * 9 + k] = h[k] * inv2;
}

extern "C" void kernel_launch(void* const* d_in, const int* in_sizes, int n_in,
                              void* d_out, int out_size, void* d_ws, size_t ws_size,
                              hipStream_t stream) {
  const float* x = (const float*)d_in[0];
  float* out = (float*)d_out;
  float* hist2 = (float*)d_ws;  // 512*16*9 floats = 294912 B

  dim3 g1(16, 512);
  phog_hist_kernel<<<g1, 256, 0, stream>>>(x, hist2);

  int total = 32 * 336;
  phog_norm_kernel<<<(total + 255) / 256, 256, 0, stream>>>(hist2, out);
}

// Round 2
// 79.835 us; speedup vs baseline: 1.1377x; 1.1377x over previous
//
#include <hip/hip_runtime.h>
#include <hip/hip_bf16.h>

// PHOG: lap = dw3x3(x, laplacian); gx,gy = dw3x3(lap, sobel); mag/ang -> 9-bin
// hist over pyramid cells (1+4+16), L1-ish then L2 normalize.
// Kernel 1: one block per (bc, 64x64 cell) -> cumulative hists A[0..8],T in ws.
//   Cumulative trick: p_i = (ang >= b_i) is monotone in i (boundaries increasing),
//   so accumulating A[i] = sum{mag : p_i} + total T recovers the histogram:
//   h[c] = A[c-1]-A[c] (c>=1), h[0] = (T-A[0]) + A[8].  No per-pixel scatter.
// Kernel 2: aggregate levels, normalize, write out [32][1][336][9].

#define H_IMG 256
#define W_IMG 256

__device__ __forceinline__ void load_xrow(const float* xs, int row, int cb, float r[8]) {
  const float* p = xs + row * 72 + cb;   // cb is even -> 8B aligned
  float2 a = *reinterpret_cast<const float2*>(p);
  float2 b = *reinterpret_cast<const float2*>(p + 2);
  float2 c = *reinterpret_cast<const float2*>(p + 4);
  float2 d = *reinterpret_cast<const float2*>(p + 6);
  r[0] = a.x; r[1] = a.y; r[2] = b.x; r[3] = b.y;
  r[4] = c.x; r[5] = c.y; r[6] = d.x; r[7] = d.y;
}

// lap row from x rows u (above), m (center), d (below); mask edge cols/rows to 0
__device__ __forceinline__ void lap_row(float dst[6], const float u[8], const float m[8],
                                        const float d[8], float wm0, float wm5, float rowm) {
#pragma unroll
  for (int c = 0; c < 6; ++c) {
    float v = (u[c + 1] + d[c + 1]) + fmaf(-4.f, m[c + 1], m[c] + m[c + 2]);
    dst[c] = v * rowm;
  }
  dst[0] *= wm0;
  dst[5] *= wm5;
}

// gradient + cumulative-binning for one output row (4 px) from lap rows A,B,C
// acc[0..8] = cumulative sums (mag where ang >= b_i), acc[9] = total mag
__device__ __forceinline__ void out_row(const float A[6], const float B[6], const float C[6],
                                        float acc[10]) {
  float cs[6], dd[6];
#pragma unroll
  for (int c = 0; c < 6; ++c) {
    cs[c] = A[c] + fmaf(2.f, B[c], C[c]);
    dd[c] = C[c] - A[c];
  }
#pragma unroll
  for (int c = 0; c < 4; ++c) {
    float gx = cs[c + 2] - cs[c];
    float gy = fmaf(2.f, dd[c + 1], dd[c] + dd[c + 2]);
    float mag = __builtin_amdgcn_sqrtf(fmaf(gx, gx, fmaf(gy, gy, 1e-8f)));
    // normalize direction to upper half-plane (ang in [0,180))
    bool neg = gy < 0.f;
    float fx = neg ? -gx : gx;
    float fy = neg ? -gy : gy;
    // boundary b_i = 10+20i deg; p_i = (ang>=b_i) <=> sin(b_i)*fx <= cos(b_i)*fy
    // mirror pair: p_{8-i} <=> sin(b_i)*fx <= -cos(b_i)*fy  (neg modifier = free)
    float u, v;
    u = 0.17364817766693033f * fx; v = 0.984807753012208f * fy;
    acc[0] += (u <= v) ? mag : 0.f;
    acc[8] += (u <= -v) ? mag : 0.f;
    u = 0.5f * fx; v = 0.8660254037844387f * fy;
    acc[1] += (u <= v) ? mag : 0.f;
    acc[7] += (u <= -v) ? mag : 0.f;
    u = 0.766044443118978f * fx; v = 0.6427876096865393f * fy;
    acc[2] += (u <= v) ? mag : 0.f;
    acc[6] += (u <= -v) ? mag : 0.f;
    u = 0.9396926207859084f * fx; v = 0.3420201433256687f * fy;
    acc[3] += (u <= v) ? mag : 0.f;
    acc[5] += (u <= -v) ? mag : 0.f;
    acc[4] += (fx <= 0.f) ? mag : 0.f;
    acc[9] += mag;
  }
}

__global__ __launch_bounds__(256) void phog_hist_kernel(const float* __restrict__ x,
                                                        float* __restrict__ hist2) {
  const int tile = blockIdx.x;  // 0..15 == level-2 cell id (cellr*4+cellc)
  const int bc = blockIdx.y;    // 0..511
  const int R0 = (tile >> 2) * 64;
  const int C0 = (tile & 3) * 64;
  const int tid = threadIdx.x;

  __shared__ float xs[68 * 72];  // rows R0-2..R0+65, cols C0-4..C0+67
  __shared__ float hred[4][10];
  __shared__ float hsum[10];

  const float* xim = x + (size_t)bc * (H_IMG * W_IMG);

  // Stage A: global -> LDS, float4 aligned (col base C0-4 is 4-aligned)
  for (int i = tid; i < 68 * 18; i += 256) {
    int row = i / 18;
    int c4 = i - row * 18;
    int gr = R0 + row - 2;
    int gc = C0 + c4 * 4 - 4;
    float4 v;
    if ((unsigned)gr < 256u && (unsigned)gc < 253u) {
      v = *reinterpret_cast<const float4*>(&xim[gr * W_IMG + gc]);
    } else if ((unsigned)gr < 256u) {
      v.x = ((unsigned)(gc + 0) < 256u) ? xim[gr * W_IMG + gc + 0] : 0.f;
      v.y = ((unsigned)(gc + 1) < 256u) ? xim[gr * W_IMG + gc + 1] : 0.f;
      v.z = ((unsigned)(gc + 2) < 256u) ? xim[gr * W_IMG + gc + 2] : 0.f;
      v.w = ((unsigned)(gc + 3) < 256u) ? xim[gr * W_IMG + gc + 3] : 0.f;
    } else {
      v = make_float4(0.f, 0.f, 0.f, 0.f);
    }
    *reinterpret_cast<float4*>(&xs[row * 72 + c4 * 4]) = v;
  }
  __syncthreads();

  const int tcol = tid & 15;
  const int trow = tid >> 4;
  const int cb = 4 * tcol + 2;  // xs col of window col 0 (global C0+4*tcol-2)

  // edge masks: lap values at global row/col -1 or 256 must be zero
  float wm0 = (C0 + 4 * tcol - 1 >= 0) ? 1.f : 0.f;
  float wm5 = (C0 + 4 * tcol + 4 <= 255) ? 1.f : 0.f;
  float rm0 = (R0 + 4 * trow - 1 >= 0) ? 1.f : 0.f;
  float rm5 = (R0 + 4 * trow + 4 <= 255) ? 1.f : 0.f;

  float acc[10];
#pragma unroll
  for (int k = 0; k < 10; ++k) acc[k] = 0.f;

  float xr0[8], xr1[8], xr2[8], lA[6], lB[6], lC[6];
  const int rb = 4 * trow;

  load_xrow(xs, rb + 0, cb, xr0);
  load_xrow(xs, rb + 1, cb, xr1);
  load_xrow(xs, rb + 2, cb, xr2);
  lap_row(lA, xr0, xr1, xr2, wm0, wm5, rm0);      // lap row 0
  load_xrow(xs, rb + 3, cb, xr0);
  lap_row(lB, xr1, xr2, xr0, wm0, wm5, 1.f);      // lap row 1
  load_xrow(xs, rb + 4, cb, xr1);
  lap_row(lC, xr2, xr0, xr1, wm0, wm5, 1.f);      // lap row 2
  out_row(lA, lB, lC, acc);                       // out row 0
  load_xrow(xs, rb + 5, cb, xr2);
  lap_row(lA, xr0, xr1, xr2, wm0, wm5, 1.f);      // lap row 3
  out_row(lB, lC, lA, acc);                       // out row 1
  load_xrow(xs, rb + 6, cb, xr0);
  lap_row(lB, xr1, xr2, xr0, wm0, wm5, 1.f);      // lap row 4
  out_row(lC, lA, lB, acc);                       // out row 2
  load_xrow(xs, rb + 7, cb, xr1);
  lap_row(lC, xr2, xr0, xr1, wm0, wm5, rm5);      // lap row 5
  out_row(lA, lB, lC, acc);                       // out row 3

  // wave reduce (64 lanes), then cross-wave via LDS
#pragma unroll
  for (int k = 0; k < 10; ++k) {
    float v = acc[k];
#pragma unroll
    for (int off = 32; off > 0; off >>= 1) v += __shfl_xor(v, off);
    acc[k] = v;
  }
  int lane = tid & 63;
  int wave = tid >> 6;
  if (lane == 0) {
#pragma unroll
    for (int k = 0; k < 10; ++k) hred[wave][k] = acc[k];
  }
  __syncthreads();
  if (tid < 10) {
    hsum[tid] = (hred[0][tid] + hred[1][tid]) + (hred[2][tid] + hred[3][tid]);
  }
  __syncthreads();
  if (tid < 9) {
    // convert cumulative sums back to histogram bins
    float h = (tid == 0) ? ((hsum[9] - hsum[0]) + hsum[8]) : (hsum[tid - 1] - hsum[tid]);
    hist2[(bc * 16 + tile) * 9 + tid] = h;
  }
}

__global__ __launch_bounds__(256) void phog_norm_kernel(const float* __restrict__ hist2,
                                                        float* __restrict__ out) {
  int t = blockIdx.x * 256 + threadIdx.x;
  if (t >= 32 * 336) return;
  int b = t / 336;
  int r = t - b * 336;

  float h[9];
  if (r < 16) {
    // level 0: sum all 16 cells of channel c=r
    const float* p = hist2 + (b * 16 + r) * 144;
#pragma unroll
    for (int k = 0; k < 9; ++k) {
      float s = 0.f;
#pragma unroll
      for (int cell = 0; cell < 16; ++cell) s += p[cell * 9 + k];
      h[k] = s;
    }
  } else if (r < 80) {
    // level 1: 4 cells per channel; cell (r1,c1) = sum of 2x2 level-2 cells
    int q = r - 16;
    int c = q >> 2;
    int cell = q & 3;
    int r1 = cell >> 1, c1 = cell & 1;
    const float* p = hist2 + (b * 16 + c) * 144;
    int i00 = ((2 * r1) * 4 + 2 * c1) * 9;
    int i01 = ((2 * r1) * 4 + 2 * c1 + 1) * 9;
    int i10 = ((2 * r1 + 1) * 4 + 2 * c1) * 9;
    int i11 = ((2 * r1 + 1) * 4 + 2 * c1 + 1) * 9;
#pragma unroll
    for (int k = 0; k < 9; ++k) h[k] = (p[i00 + k] + p[i01 + k]) + (p[i10 + k] + p[i11 + k]);
  } else {
    // level 2: direct
    int q = r - 80;
    int c = q >> 4;
    int cell = q & 15;
    const float* p = hist2 + ((b * 16 + c) * 16 + cell) * 9;
#pragma unroll
    for (int k = 0; k < 9; ++k) h[k] = p[k];
  }

  float s = 0.f;
#pragma unroll
  for (int k = 0; k < 9; ++k) s += h[k];
  float inv = 1.f / (s + 1e-8f);
#pragma unroll
  for (int k = 0; k < 9; ++k) h[k] *= inv;
  float n2 = 0.f;
#pragma unroll
  for (int k = 0; k < 9; ++k) n2 = fmaf(h[k], h[k], n2);
  float nrm = sqrtf(n2);
  float inv2 = 1.f / fmaxf(nrm, 1e-12f);
#pragma unroll
  for (int k = 0; k < 9; ++k) out[t * 9 + k] = h[k] * inv2;
}

extern "C" void kernel_launch(void* const* d_in, const int* in_sizes, int n_in,
                              void* d_out, int out_size, void* d_ws, size_t ws_size,
                              hipStream_t stream) {
  const float* x = (const float*)d_in[0];
  float* out = (float*)d_out;
  float* hist2 = (float*)d_ws;  // 512*16*9 floats = 294912 B

  dim3 g1(16, 512);
  phog_hist_kernel<<<g1, 256, 0, stream>>>(x, hist2);

  int total = 32 * 336;
  phog_norm_kernel<<<(total + 255) / 256, 256, 0, stream>>>(hist2, out);
}